// Round 3
// baseline (1781.303 us; speedup 1.0000x reference)
//
#include <hip/hip_runtime.h>
#include <hip/hip_bf16.h>

// 3-layer stacked LSTM forward (eval), fp32 throughout (correctness + baseline).
// T=512, B=256, IN=97, H1=128, H2=64, H3=1.
//
// Structure:
//  - gemm_xg:    xg = X * W^T + b1 + b2   (generic fp32 tiled GEMM, 64x64 tile, K<=128)
//  - lstm_scan<H>: per-batch-row recurrent scan, Whh in registers, h broadcast via LDS
//  - gemm_xg3 / lstm_scan3: tiny layer-3 path
//
// Layer-1/2 xg buffers are chunked over T (CH=128) to cap workspace at ~204 MB.
//
// (2nd resubmission: rounds 1 and 2 both died with UnresponsiveContainer broker
// errors before any compile/run signal was produced.)

#define T_TOT 512
#define BB    256
#define CH    128
#define NCH   4

__device__ __forceinline__ float sigm(float x) {
    float e = __expf(-x);
    return __builtin_amdgcn_rcpf(1.0f + e);
}
__device__ __forceinline__ float tanh_(float x) {
    // tanh(x) = 1 - 2/(exp(2x)+1); saturates correctly at +-inf
    float e = __expf(2.0f * x);
    return 1.0f - 2.0f * __builtin_amdgcn_rcpf(1.0f + e);
}

// ---------------------------------------------------------------------------
// Generic xg GEMM: out[m,n] = sum_k X[m,k]*W[n,k] + b1[n] + b2[n]
// grid = (M/64, N/64), block = 256. K <= 128. M,N multiples of 64.
// ---------------------------------------------------------------------------
__global__ __launch_bounds__(256) void gemm_xg(
    const float* __restrict__ X,   // [M, K]
    const float* __restrict__ W,   // [N, K]
    const float* __restrict__ b1,
    const float* __restrict__ b2,
    float* __restrict__ out,       // [M, N]
    int N, int K)
{
    __shared__ __align__(16) float xs[128][68];
    __shared__ __align__(16) float wsh[128][68];

    const int tid  = threadIdx.x;
    const int m0   = blockIdx.x * 64;
    const int n0   = blockIdx.y * 64;
    const int lane = tid & 63;
    const int wid  = tid >> 6;   // 0..3

    // Stage X tile transposed: xs[k][r]
    for (int r = wid; r < 64; r += 4) {
        const float* xr = X + (size_t)(m0 + r) * K;
        for (int k = lane; k < K; k += 64) xs[k][r] = xr[k];
    }
    // Stage W tile transposed: wsh[k][c]
    for (int r = wid; r < 64; r += 4) {
        const float* wr = W + (size_t)(n0 + r) * K;
        for (int k = lane; k < K; k += 64) wsh[k][r] = wr[k];
    }
    __syncthreads();

    const int tx = tid & 15;   // n-sub
    const int ty = tid >> 4;   // m-sub
    float acc[4][4] = {};

    for (int k = 0; k < K; ++k) {
        float4 xv  = *reinterpret_cast<const float4*>(&xs[k][ty * 4]);
        float4 wv  = *reinterpret_cast<const float4*>(&wsh[k][tx * 4]);
        float xr4[4] = {xv.x, xv.y, xv.z, xv.w};
        float wr4[4] = {wv.x, wv.y, wv.z, wv.w};
#pragma unroll
        for (int i = 0; i < 4; ++i)
#pragma unroll
            for (int j = 0; j < 4; ++j)
                acc[i][j] = fmaf(xr4[i], wr4[j], acc[i][j]);
    }

    const int n = n0 + tx * 4;
    float bs[4];
#pragma unroll
    for (int j = 0; j < 4; ++j) bs[j] = b1[n + j] + b2[n + j];

#pragma unroll
    for (int i = 0; i < 4; ++i) {
        const int m = m0 + ty * 4 + i;
        float4 o;
        o.x = acc[i][0] + bs[0];
        o.y = acc[i][1] + bs[1];
        o.z = acc[i][2] + bs[2];
        o.w = acc[i][3] + bs[3];
        *reinterpret_cast<float4*>(&out[(size_t)m * N + n]) = o;
    }
}

// ---------------------------------------------------------------------------
// Recurrent scan for layers 1/2. One block per batch row, 4H threads.
// Thread n owns gate-row n of Whh (H floats in registers).
// ---------------------------------------------------------------------------
template <int H>
__global__ __launch_bounds__(4 * H) void lstm_scan(
    const float* __restrict__ xg,     // [Tc, B, 4H]  (bias already included)
    const float* __restrict__ Whh,    // [4H, H]
    float* __restrict__ hout,         // [Tc, B, H]
    float* __restrict__ hstate,       // [B, H] persistent across chunks
    float* __restrict__ cstate,       // [B, H]
    int Tc, int first)
{
    constexpr int N4 = 4 * H;
    const int n   = threadIdx.x;
    const int row = blockIdx.x;

    __shared__ __align__(16) float h_lds[H];
    __shared__ __align__(16) float g_lds[N4];

    // Whh row n into registers (one-time, L3-resident across blocks)
    float4 wv[H / 4];
    const float4* wr = reinterpret_cast<const float4*>(Whh + (size_t)n * H);
#pragma unroll
    for (int i = 0; i < H / 4; ++i) wv[i] = wr[i];

    float c = 0.0f;
    if (n < H) {
        c        = first ? 0.0f : cstate[row * H + n];
        h_lds[n] = first ? 0.0f : hstate[row * H + n];
    }
    __syncthreads();

    const float* p = xg + (size_t)row * N4 + n;
    float nxt = p[0];

    for (int t = 0; t < Tc; ++t) {
        float acc = nxt;
        if (t + 1 < Tc) nxt = p[(size_t)(t + 1) * BB * N4];  // prefetch next step

#pragma unroll
        for (int i = 0; i < H / 4; ++i) {
            float4 hv = *reinterpret_cast<const float4*>(&h_lds[4 * i]);
            acc = fmaf(hv.x, wv[i].x, acc);
            acc = fmaf(hv.y, wv[i].y, acc);
            acc = fmaf(hv.z, wv[i].z, acc);
            acc = fmaf(hv.w, wv[i].w, acc);
        }
        g_lds[n] = acc;
        __syncthreads();

        if (n < H) {
            float gi = g_lds[n];
            float gf = g_lds[n + H];
            float gg = g_lds[n + 2 * H];
            float go = g_lds[n + 3 * H];
            float i_ = sigm(gi);
            float f_ = sigm(gf);
            float g_ = tanh_(gg);
            float o_ = sigm(go);
            c = fmaf(f_, c, i_ * g_);
            float h = o_ * tanh_(c);
            h_lds[n] = h;
            hout[((size_t)t * BB + row) * H + n] = h;
        }
        __syncthreads();
    }

    if (n < H) {
        cstate[row * H + n] = c;
        hstate[row * H + n] = h_lds[n];
    }
}

// ---------------------------------------------------------------------------
// Layer-3 input GEMM: out[m, 0..3] = sum_k X[m,k]*W[n,k] + b, K=64, N=4
// grid = M/256, block = 256, one row per thread.
// ---------------------------------------------------------------------------
__global__ __launch_bounds__(256) void gemm_xg3(
    const float* __restrict__ X,   // [M, 64]
    const float* __restrict__ W,   // [4, 64]
    const float* __restrict__ b1,
    const float* __restrict__ b2,
    float* __restrict__ out)       // [M, 4]
{
    __shared__ __align__(16) float ws4[4][64];
    __shared__ float bb[4];
    const int tid = threadIdx.x;
    {
        const int nn = tid >> 6, kk = tid & 63;
        ws4[nn][kk] = W[nn * 64 + kk];
    }
    if (tid < 4) bb[tid] = b1[tid] + b2[tid];
    __syncthreads();

    const int m = blockIdx.x * 256 + tid;
    const float4* xr = reinterpret_cast<const float4*>(X + (size_t)m * 64);
    float a0 = bb[0], a1 = bb[1], a2 = bb[2], a3 = bb[3];
#pragma unroll
    for (int kk = 0; kk < 16; ++kk) {
        float4 xv = xr[kk];
        float4 w0 = *reinterpret_cast<const float4*>(&ws4[0][4 * kk]);
        float4 w1 = *reinterpret_cast<const float4*>(&ws4[1][4 * kk]);
        float4 w2 = *reinterpret_cast<const float4*>(&ws4[2][4 * kk]);
        float4 w3 = *reinterpret_cast<const float4*>(&ws4[3][4 * kk]);
        a0 = fmaf(xv.x, w0.x, a0); a0 = fmaf(xv.y, w0.y, a0); a0 = fmaf(xv.z, w0.z, a0); a0 = fmaf(xv.w, w0.w, a0);
        a1 = fmaf(xv.x, w1.x, a1); a1 = fmaf(xv.y, w1.y, a1); a1 = fmaf(xv.z, w1.z, a1); a1 = fmaf(xv.w, w1.w, a1);
        a2 = fmaf(xv.x, w2.x, a2); a2 = fmaf(xv.y, w2.y, a2); a2 = fmaf(xv.z, w2.z, a2); a2 = fmaf(xv.w, w2.w, a2);
        a3 = fmaf(xv.x, w3.x, a3); a3 = fmaf(xv.y, w3.y, a3); a3 = fmaf(xv.z, w3.z, a3); a3 = fmaf(xv.w, w3.w, a3);
    }
    float4 o; o.x = a0; o.y = a1; o.z = a2; o.w = a3;
    *reinterpret_cast<float4*>(&out[(size_t)m * 4]) = o;
}

// ---------------------------------------------------------------------------
// Layer-3 scan: H=1. One block, 256 threads = 256 batch rows, scalar h,c.
// ---------------------------------------------------------------------------
__global__ __launch_bounds__(256) void lstm_scan3(
    const float* __restrict__ xg,   // [T, B, 4]
    const float* __restrict__ Whh,  // [4, 1]
    float* __restrict__ out,        // [T, B]
    int T)
{
    const int b = threadIdx.x;
    const float w0 = Whh[0], w1 = Whh[1], w2 = Whh[2], w3 = Whh[3];
    float h = 0.0f, c = 0.0f;
    const float4* p = reinterpret_cast<const float4*>(xg) + b;
    float4 nxt = p[0];
    for (int t = 0; t < T; ++t) {
        float4 g4 = nxt;
        if (t + 1 < T) nxt = p[(size_t)(t + 1) * BB];
        float gi = fmaf(h, w0, g4.x);
        float gf = fmaf(h, w1, g4.y);
        float gg = fmaf(h, w2, g4.z);
        float go = fmaf(h, w3, g4.w);
        float i_ = sigm(gi);
        float f_ = sigm(gf);
        float g_ = tanh_(gg);
        float o_ = sigm(go);
        c = fmaf(f_, c, i_ * g_);
        h = o_ * tanh_(c);
        out[(size_t)t * BB + b] = h;
    }
}

// ---------------------------------------------------------------------------
extern "C" void kernel_launch(void* const* d_in, const int* in_sizes, int n_in,
                              void* d_out, int out_size, void* d_ws, size_t ws_size,
                              hipStream_t stream) {
    const float* x    = (const float*)d_in[0];
    const float* Wih1 = (const float*)d_in[1];
    const float* Whh1 = (const float*)d_in[2];
    const float* bih1 = (const float*)d_in[3];
    const float* bhh1 = (const float*)d_in[4];
    const float* Wih2 = (const float*)d_in[5];
    const float* Whh2 = (const float*)d_in[6];
    const float* bih2 = (const float*)d_in[7];
    const float* bhh2 = (const float*)d_in[8];
    const float* Wih3 = (const float*)d_in[9];
    const float* Whh3 = (const float*)d_in[10];
    const float* bih3 = (const float*)d_in[11];
    const float* bhh3 = (const float*)d_in[12];
    float* out = (float*)d_out;

    char* ws = (char*)d_ws;
    // Workspace layout (bytes), total ~204 MB:
    float* xg1c = (float*)(ws + 0);                       // [CH,B,512] fp32 = 67,108,864
    float* h1   = (float*)(ws + 67108864);                // [T,B,128]  fp32 = 67,108,864
    float* xg2c = (float*)(ws + 134217728);               // [CH,B,256] fp32 = 33,554,432
    float* h2   = (float*)(ws + 167772160);               // [T,B,64]   fp32 = 33,554,432
    float* xg3  = (float*)(ws + 201326592);               // [T,B,4]    fp32 =  2,097,152
    float* st1h = (float*)(ws + 203423744);               // [B,128]
    float* st1c = st1h + BB * 128;
    float* st2h = st1c + BB * 128;                        // [B,64]
    float* st2c = st2h + BB * 64;

    // ---- Layer 1 (chunked over T) ----
    for (int c0 = 0; c0 < NCH; ++c0) {
        gemm_xg<<<dim3(CH * BB / 64, 512 / 64), 256, 0, stream>>>(
            x + (size_t)c0 * CH * BB * 97, Wih1, bih1, bhh1, xg1c, 512, 97);
        lstm_scan<128><<<BB, 512, 0, stream>>>(
            xg1c, Whh1, h1 + (size_t)c0 * CH * BB * 128, st1h, st1c, CH, c0 == 0);
    }
    // ---- Layer 2 (chunked over T) ----
    for (int c0 = 0; c0 < NCH; ++c0) {
        gemm_xg<<<dim3(CH * BB / 64, 256 / 64), 256, 0, stream>>>(
            h1 + (size_t)c0 * CH * BB * 128, Wih2, bih2, bhh2, xg2c, 256, 128);
        lstm_scan<64><<<BB, 256, 0, stream>>>(
            xg2c, Whh2, h2 + (size_t)c0 * CH * BB * 64, st2h, st2c, CH, c0 == 0);
    }
    // ---- Layer 3 ----
    gemm_xg3<<<T_TOT * BB / 256, 256, 0, stream>>>(h2, Wih3, bih3, bhh3, xg3);
    lstm_scan3<<<1, 256, 0, stream>>>(xg3, Whh3, out, T_TOT);
}

// Round 4
// 1091.005 us; speedup vs baseline: 1.6327x; 1.6327x over previous
//
#include <hip/hip_runtime.h>
#include <hip/hip_bf16.h>

// 3-layer stacked LSTM forward (eval). Round 4:
//  - Input GEMMs for layers 1/2 -> bf16 MFMA (16x16x32), 128x128 tile, 4 waves,
//    B(weights) in registers from L2, A staged in LDS with XOR swizzle (T2).
//  - Layer-3 GEMM + all recurrent scans stay fp32 (error budget: keep gate-path
//    noise sources limited to the two big GEMMs; measured fp32 floor was 2^-10).
//  - scan1 writes h1 as bf16 (only consumer is GEMM2).
// T=512, B=256, IN=97(pad 128), H1=128, H2=64, H3=1.

#define T_TOT 512
#define BB    256
#define CH    128
#define NCH   4

typedef __attribute__((ext_vector_type(8))) short  short8v;   // 8 bf16
typedef __attribute__((ext_vector_type(4))) float  float4v;   // MFMA acc

__device__ __forceinline__ float sigm(float x) {
    float e = __expf(-x);
    return __builtin_amdgcn_rcpf(1.0f + e);
}
__device__ __forceinline__ float tanh_(float x) {
    float e = __expf(2.0f * x);
    return 1.0f - 2.0f * __builtin_amdgcn_rcpf(1.0f + e);
}

// ---------------------------------------------------------------------------
// cvt_pad: [R,K] fp32 -> [R,128] bf16, zero-padded cols K..127.
// ---------------------------------------------------------------------------
__global__ __launch_bounds__(256) void cvt_pad(
    const float* __restrict__ in, __hip_bfloat16* __restrict__ out, int R, int K)
{
    int total = R * 128;
    for (int idx = blockIdx.x * 256 + threadIdx.x; idx < total; idx += gridDim.x * 256) {
        int r = idx >> 7, c = idx & 127;
        float v = (c < K) ? in[(size_t)r * K + c] : 0.0f;
        out[idx] = __float2bfloat16(v);
    }
}

__global__ __launch_bounds__(256) void addvec(
    const float* __restrict__ a, const float* __restrict__ b, float* __restrict__ o, int n)
{
    int i = blockIdx.x * 256 + threadIdx.x;
    if (i < n) o[i] = a[i] + b[i];
}

// ---------------------------------------------------------------------------
// bf16 MFMA GEMM: C[M,N] = A[M,128]bf16 * W[N,128]bf16^T + bias[n]
// grid = (M/128, N/128), block = 256 (4 waves, 2x2), wave tile 64x64.
// A tile in LDS, XOR-swizzled (byte ^= (row&7)<<4) against the 256B-row-stride
// 16-way bank conflict on ds_read_b128 (G4/T2). W frags live in registers
// (4x4 x 16B/lane = 64 VGPR), loaded once per block from L2.
// ---------------------------------------------------------------------------
__global__ __launch_bounds__(256) void gemm_mfma(
    const __hip_bfloat16* __restrict__ A,
    const __hip_bfloat16* __restrict__ W,
    const float* __restrict__ bias,
    float* __restrict__ C, int N)
{
    __shared__ __hip_bfloat16 At[128 * 128];   // 32 KB

    const int tid  = threadIdx.x;
    const int lane = tid & 63;
    const int wid  = tid >> 6;     // 0..3
    const int m0   = blockIdx.x * 128;
    const int n0   = blockIdx.y * 128;
    const int wr   = wid >> 1;     // 0..1 (m half)
    const int wc   = wid & 1;      // 0..1 (n half)

    // ---- B fragments: lane holds W[n0+wc*64+nf*16+(lane&15)][kf*32+(lane>>4)*8 +0..7]
    short8v bfrag[4][4];  // [nf][kf]
    {
        const char* Wg = (const char*)W;
#pragma unroll
        for (int nf = 0; nf < 4; ++nf) {
            int row = n0 + wc * 64 + nf * 16 + (lane & 15);
#pragma unroll
            for (int kf = 0; kf < 4; ++kf) {
                int colb = (kf * 32 + (lane >> 4) * 8) * 2;
                bfrag[nf][kf] = *(const short8v*)(Wg + (size_t)row * 256 + colb);
            }
        }
    }

    // ---- Stage A tile -> LDS (swizzled dest, linear source) ----
    {
        const char* Ag = (const char*)(A + (size_t)m0 * 128);
        char* As = (char*)At;
#pragma unroll
        for (int r2 = 0; r2 < 8; ++r2) {
            int off = r2 * 4096 + tid * 16;   // linear byte offset in tile
            int row = off >> 8;               // 256 B per row (128 bf16)
            int bir = off & 255;
            short8v v = *(const short8v*)(Ag + (size_t)row * 256 + bir);
            int sw = bir ^ ((row & 7) << 4);
            *(short8v*)(As + row * 256 + sw) = v;
        }
    }
    __syncthreads();

    float4v acc[4][4] = {};   // [mf][nf], all indices compile-time (rule #20)

#pragma unroll
    for (int kf = 0; kf < 4; ++kf) {
        short8v af[4];
#pragma unroll
        for (int mf = 0; mf < 4; ++mf) {
            int row   = wr * 64 + mf * 16 + (lane & 15);
            int kbyte = kf * 64 + (lane >> 4) * 16;
            int sw    = kbyte ^ ((row & 7) << 4);
            af[mf] = *(const short8v*)((const char*)At + row * 256 + sw);
        }
#pragma unroll
        for (int mf = 0; mf < 4; ++mf)
#pragma unroll
            for (int nf = 0; nf < 4; ++nf)
                acc[mf][nf] = __builtin_amdgcn_mfma_f32_16x16x32_bf16(
                    af[mf], bfrag[nf][kf], acc[mf][nf], 0, 0, 0);
    }

    // ---- Epilogue: C[row][col] = acc + bias[col]; col=lane&15, row=(lane>>4)*4+r
#pragma unroll
    for (int nf = 0; nf < 4; ++nf) {
        int col = n0 + wc * 64 + nf * 16 + (lane & 15);
        float bv = bias[col];
#pragma unroll
        for (int mf = 0; mf < 4; ++mf) {
            int rbase = m0 + wr * 64 + mf * 16 + (lane >> 4) * 4;
#pragma unroll
            for (int r = 0; r < 4; ++r)
                C[(size_t)(rbase + r) * N + col] = acc[mf][nf][r] + bv;
        }
    }
}

// ---------------------------------------------------------------------------
// Recurrent scan, layers 1/2 (unchanged logic; output type templated so
// scan1 can emit bf16 h1 for the bf16 GEMM2).
// ---------------------------------------------------------------------------
__device__ __forceinline__ void storev(float* p, float v) { *p = v; }
__device__ __forceinline__ void storev(__hip_bfloat16* p, float v) { *p = __float2bfloat16(v); }

template <int H, typename OutT>
__global__ __launch_bounds__(4 * H) void lstm_scan(
    const float* __restrict__ xg,     // [Tc, B, 4H] bias included
    const float* __restrict__ Whh,    // [4H, H]
    OutT* __restrict__ hout,          // [Tc, B, H]
    float* __restrict__ hstate,       // [B, H]
    float* __restrict__ cstate,       // [B, H]
    int Tc, int first)
{
    constexpr int N4 = 4 * H;
    const int n   = threadIdx.x;
    const int row = blockIdx.x;

    __shared__ __align__(16) float h_lds[H];
    __shared__ __align__(16) float g_lds[N4];

    float4 wv[H / 4];
    const float4* wr = reinterpret_cast<const float4*>(Whh + (size_t)n * H);
#pragma unroll
    for (int i = 0; i < H / 4; ++i) wv[i] = wr[i];

    float c = 0.0f;
    if (n < H) {
        c        = first ? 0.0f : cstate[row * H + n];
        h_lds[n] = first ? 0.0f : hstate[row * H + n];
    }
    __syncthreads();

    const float* p = xg + (size_t)row * N4 + n;
    float nxt = p[0];

    for (int t = 0; t < Tc; ++t) {
        float acc = nxt;
        if (t + 1 < Tc) nxt = p[(size_t)(t + 1) * BB * N4];

#pragma unroll
        for (int i = 0; i < H / 4; ++i) {
            float4 hv = *reinterpret_cast<const float4*>(&h_lds[4 * i]);
            acc = fmaf(hv.x, wv[i].x, acc);
            acc = fmaf(hv.y, wv[i].y, acc);
            acc = fmaf(hv.z, wv[i].z, acc);
            acc = fmaf(hv.w, wv[i].w, acc);
        }
        g_lds[n] = acc;
        __syncthreads();

        if (n < H) {
            float gi = g_lds[n];
            float gf = g_lds[n + H];
            float gg = g_lds[n + 2 * H];
            float go = g_lds[n + 3 * H];
            float i_ = sigm(gi);
            float f_ = sigm(gf);
            float g_ = tanh_(gg);
            float o_ = sigm(go);
            c = fmaf(f_, c, i_ * g_);
            float h = o_ * tanh_(c);
            h_lds[n] = h;
            storev(&hout[((size_t)t * BB + row) * H + n], h);
        }
        __syncthreads();
    }

    if (n < H) {
        cstate[row * H + n] = c;
        hstate[row * H + n] = h_lds[n];
    }
}

// ---------------------------------------------------------------------------
// Layer-3 input GEMM (fp32, unchanged): out[m,0..3] = sum_k X[m,k]*W[n,k] + b
// ---------------------------------------------------------------------------
__global__ __launch_bounds__(256) void gemm_xg3(
    const float* __restrict__ X,   // [M, 64]
    const float* __restrict__ W,   // [4, 64]
    const float* __restrict__ b1,
    const float* __restrict__ b2,
    float* __restrict__ out)       // [M, 4]
{
    __shared__ __align__(16) float ws4[4][64];
    __shared__ float bb[4];
    const int tid = threadIdx.x;
    {
        const int nn = tid >> 6, kk = tid & 63;
        ws4[nn][kk] = W[nn * 64 + kk];
    }
    if (tid < 4) bb[tid] = b1[tid] + b2[tid];
    __syncthreads();

    const int m = blockIdx.x * 256 + tid;
    const float4* xr = reinterpret_cast<const float4*>(X + (size_t)m * 64);
    float a0 = bb[0], a1 = bb[1], a2 = bb[2], a3 = bb[3];
#pragma unroll
    for (int kk = 0; kk < 16; ++kk) {
        float4 xv = xr[kk];
        float4 w0 = *reinterpret_cast<const float4*>(&ws4[0][4 * kk]);
        float4 w1 = *reinterpret_cast<const float4*>(&ws4[1][4 * kk]);
        float4 w2 = *reinterpret_cast<const float4*>(&ws4[2][4 * kk]);
        float4 w3 = *reinterpret_cast<const float4*>(&ws4[3][4 * kk]);
        a0 = fmaf(xv.x, w0.x, a0); a0 = fmaf(xv.y, w0.y, a0); a0 = fmaf(xv.z, w0.z, a0); a0 = fmaf(xv.w, w0.w, a0);
        a1 = fmaf(xv.x, w1.x, a1); a1 = fmaf(xv.y, w1.y, a1); a1 = fmaf(xv.z, w1.z, a1); a1 = fmaf(xv.w, w1.w, a1);
        a2 = fmaf(xv.x, w2.x, a2); a2 = fmaf(xv.y, w2.y, a2); a2 = fmaf(xv.z, w2.z, a2); a2 = fmaf(xv.w, w2.w, a2);
        a3 = fmaf(xv.x, w3.x, a3); a3 = fmaf(xv.y, w3.y, a3); a3 = fmaf(xv.z, w3.z, a3); a3 = fmaf(xv.w, w3.w, a3);
    }
    float4 o; o.x = a0; o.y = a1; o.z = a2; o.w = a3;
    *reinterpret_cast<float4*>(&out[(size_t)m * 4]) = o;
}

// ---------------------------------------------------------------------------
// Layer-3 scan (fp32, unchanged): one block, 256 threads = 256 batch rows.
// ---------------------------------------------------------------------------
__global__ __launch_bounds__(256) void lstm_scan3(
    const float* __restrict__ xg,   // [T, B, 4]
    const float* __restrict__ Whh,  // [4, 1]
    float* __restrict__ out,        // [T, B]
    int T)
{
    const int b = threadIdx.x;
    const float w0 = Whh[0], w1 = Whh[1], w2 = Whh[2], w3 = Whh[3];
    float h = 0.0f, c = 0.0f;
    const float4* p = reinterpret_cast<const float4*>(xg) + b;
    float4 nxt = p[0];
    for (int t = 0; t < T; ++t) {
        float4 g4 = nxt;
        if (t + 1 < T) nxt = p[(size_t)(t + 1) * BB];
        float gi = fmaf(h, w0, g4.x);
        float gf = fmaf(h, w1, g4.y);
        float gg = fmaf(h, w2, g4.z);
        float go = fmaf(h, w3, g4.w);
        float i_ = sigm(gi);
        float f_ = sigm(gf);
        float g_ = tanh_(gg);
        float o_ = sigm(go);
        c = fmaf(f_, c, i_ * g_);
        h = o_ * tanh_(c);
        out[(size_t)t * BB + b] = h;
    }
}

// ---------------------------------------------------------------------------
extern "C" void kernel_launch(void* const* d_in, const int* in_sizes, int n_in,
                              void* d_out, int out_size, void* d_ws, size_t ws_size,
                              hipStream_t stream) {
    const float* x    = (const float*)d_in[0];
    const float* Wih1 = (const float*)d_in[1];
    const float* Whh1 = (const float*)d_in[2];
    const float* bih1 = (const float*)d_in[3];
    const float* bhh1 = (const float*)d_in[4];
    const float* Wih2 = (const float*)d_in[5];
    const float* Whh2 = (const float*)d_in[6];
    const float* bih2 = (const float*)d_in[7];
    const float* bhh2 = (const float*)d_in[8];
    const float* Wih3 = (const float*)d_in[9];
    const float* Whh3 = (const float*)d_in[10];
    const float* bih3 = (const float*)d_in[11];
    const float* bhh3 = (const float*)d_in[12];
    float* out = (float*)d_out;

    char* ws = (char*)d_ws;
    // Workspace layout (bytes), total ~170.5 MB. xb aliases h2 (disjoint phases:
    // xb is read only during layer-1 GEMMs; h2 is written only after those).
    float*           xg1c = (float*)(ws + 0);                      // [CH,B,512] f32 = 67,108,864
    __hip_bfloat16*  h1b  = (__hip_bfloat16*)(ws + 67108864);      // [T,B,128] bf16 = 33,554,432
    float*           xg2c = (float*)(ws + 100663296);              // [CH,B,256] f32 = 33,554,432
    float*           h2   = (float*)(ws + 134217728);              // [T,B,64]  f32  = 33,554,432
    __hip_bfloat16*  xb   = (__hip_bfloat16*)(ws + 134217728);     // [T*B,128] bf16 (alias h2)
    float*           xg3  = (float*)(ws + 167772160);              // [T,B,4]   f32  =  2,097,152
    __hip_bfloat16*  wb1  = (__hip_bfloat16*)(ws + 169869312);     // [512,128] bf16 = 131,072
    __hip_bfloat16*  wb2  = (__hip_bfloat16*)(ws + 170000384);     // [256,128] bf16 =  65,536
    float*           bias1 = (float*)(ws + 170065920);             // [512]
    float*           bias2 = (float*)(ws + 170068992);             // [256] (pad to 3072 gap ok)
    float*           st1h  = (float*)(ws + 170072064);             // [B,128]
    float*           st1c  = st1h + BB * 128;
    float*           st2h  = st1c + BB * 128;                      // [B,64]
    float*           st2c  = st2h + BB * 64;

    // ---- P0: conversions ----
    cvt_pad<<<4096, 256, 0, stream>>>(x, xb, T_TOT * BB, 97);      // x -> bf16 padded
    cvt_pad<<<256, 256, 0, stream>>>(Wih1, wb1, 512, 97);
    cvt_pad<<<128, 256, 0, stream>>>(Wih2, wb2, 256, 128);
    addvec<<<2, 256, 0, stream>>>(bih1, bhh1, bias1, 512);
    addvec<<<1, 256, 0, stream>>>(bih2, bhh2, bias2, 256);

    // ---- P1: Layer 1 (chunked over T) ----
    for (int c0 = 0; c0 < NCH; ++c0) {
        gemm_mfma<<<dim3(CH * BB / 128, 512 / 128), 256, 0, stream>>>(
            xb + (size_t)c0 * CH * BB * 128, wb1, bias1, xg1c, 512);
        lstm_scan<128, __hip_bfloat16><<<BB, 512, 0, stream>>>(
            xg1c, Whh1, h1b + (size_t)c0 * CH * BB * 128, st1h, st1c, CH, c0 == 0);
    }
    // ---- P2: Layer 2 (chunked over T) ----
    for (int c0 = 0; c0 < NCH; ++c0) {
        gemm_mfma<<<dim3(CH * BB / 128, 256 / 128), 256, 0, stream>>>(
            h1b + (size_t)c0 * CH * BB * 128, wb2, bias2, xg2c, 256);
        lstm_scan<64, float><<<BB, 256, 0, stream>>>(
            xg2c, Whh2, h2 + (size_t)c0 * CH * BB * 64, st2h, st2c, CH, c0 == 0);
    }
    // ---- P3: Layer 3 ----
    gemm_xg3<<<T_TOT * BB / 256, 256, 0, stream>>>(h2, Wih3, bih3, bhh3, xg3);
    lstm_scan3<<<1, 256, 0, stream>>>(xg3, Whh3, out, T_TOT);
}